// Round 3
// baseline (242.609 us; speedup 1.0000x reference)
//
#include <hip/hip_runtime.h>

static constexpr int B = 4;
static constexpr int N = 8192;
static constexpr int H = 8;
static constexpr int BH = B * H;   // 32
#define EPSF 1e-6f

typedef _Float16 f16;
typedef _Float16 f16x8 __attribute__((ext_vector_type(8)));
typedef float f32x4 __attribute__((ext_vector_type(4)));

__device__ __forceinline__ float featmap(float x) {
    return x > 0.0f ? (x + 1.0f) : __expf(x);   // elu(x)+1
}

union H8 { f16x8 v; unsigned long long u[2]; };
__device__ __forceinline__ f16x8 lds_load8(const f16* p) {
    H8 r;
    r.u[0] = *(const unsigned long long*)(p);
    r.u[1] = *(const unsigned long long*)(p + 4);
    return r.v;
}
__device__ __forceinline__ unsigned pack2(float a, float b) {
    union { f16 h[2]; unsigned u; } x;
    x.h[0] = (f16)a; x.h[1] = (f16)b;
    return x.u;
}
__device__ __forceinline__ f16x8 pack8(const float4& a, const float4& b) {
    f16x8 r;
    r[0] = (f16)a.x; r[1] = (f16)a.y; r[2] = (f16)a.z; r[3] = (f16)a.w;
    r[4] = (f16)b.x; r[5] = (f16)b.y; r[6] = (f16)b.z; r[7] = (f16)b.w;
    return r;
}

// ---------------------------------------------------------------------------
// Pass 1 (MFMA): KV[bh][m][d] = sum_n V[n][m]*fK[n][d];  Ksum[bh][d] += sum_n fK[n][d]
// grid (BH, 32), block 256 (4 waves), 4 blocks/CU. Each block: 256 rows =
// 8 K-steps of 32. LDS: transposed fp16 tiles KT[d][n], VT[m][n], dbuffered.
// Wave w computes m-strip [16w,16w+16) x all 64 d via 4 MFMA per K-step.
// ---------------------------------------------------------------------------
static constexpr int ROWS1 = 256;
static constexpr int NSTEPS1 = ROWS1 / 32;   // 8

__global__ __launch_bounds__(256, 4) void kv_pass(
    const float* __restrict__ keys,
    const float* __restrict__ values,
    const float* __restrict__ mask,
    float* __restrict__ kv,     // [BH][64][64] (m,d) fp32, pre-zeroed
    float* __restrict__ ksum)   // [BH][64] fp32, pre-zeroed
{
    const int bh = blockIdx.x, b = bh >> 3, h = bh & 7;
    const int t = threadIdx.x;
    const int wave = t >> 6, lane = t & 63;
    const int p = t >> 4;          // 0..15: row-pair within K-step
    const int c = t & 15;          // float4 column (d/m group)
    const int quad = lane >> 4;    // 0..3
    const int l15 = lane & 15;
    const int n0 = blockIdx.y * ROWS1;

    __shared__ f16 KT[2][64][36];  // [buf][d][n] pitch 72B (8B-aligned frags)
    __shared__ f16 VT[2][64][36];  // [buf][m][n]
    __shared__ float Ksw[4][64];

    const float* mrow = mask + (size_t)b * N;

    // prefetch step 0
    int n = n0 + 2 * p;
    size_t g0 = ((size_t)((b * N + n) * H + h)) * 64 + c * 4;
    size_t g1 = g0 + (size_t)H * 64;
    float4 kq0 = *(const float4*)(keys + g0);
    float4 kq1 = *(const float4*)(keys + g1);
    float4 vq0 = *(const float4*)(values + g0);
    float4 vq1 = *(const float4*)(values + g1);
    float mk0 = mrow[n], mk1 = mrow[n + 1];

    f32x4 acc[4];
    #pragma unroll
    for (int i = 0; i < 4; ++i) acc[i] = (f32x4){0.f, 0.f, 0.f, 0.f};
    float ksacc[4] = {0.f, 0.f, 0.f, 0.f};

    for (int s = 0; s < NSTEPS1; ++s) {
        const int buf = s & 1;
        const float fk0[4] = {featmap(kq0.x) * mk0, featmap(kq0.y) * mk0,
                              featmap(kq0.z) * mk0, featmap(kq0.w) * mk0};
        const float fk1[4] = {featmap(kq1.x) * mk1, featmap(kq1.y) * mk1,
                              featmap(kq1.z) * mk1, featmap(kq1.w) * mk1};
        const float fv0[4] = {vq0.x, vq0.y, vq0.z, vq0.w};
        const float fv1[4] = {vq1.x, vq1.y, vq1.z, vq1.w};
        #pragma unroll
        for (int dd = 0; dd < 4; ++dd) {
            ksacc[dd] += fk0[dd] + fk1[dd];
            *(unsigned*)&KT[buf][c * 4 + dd][2 * p] = pack2(fk0[dd], fk1[dd]);
            *(unsigned*)&VT[buf][c * 4 + dd][2 * p] = pack2(fv0[dd], fv1[dd]);
        }
        // prefetch next K-step (global only; no LDS dependency)
        if (s + 1 < NSTEPS1) {
            const int nn = n0 + (s + 1) * 32 + 2 * p;
            const size_t h0 = ((size_t)((b * N + nn) * H + h)) * 64 + c * 4;
            const size_t h1 = h0 + (size_t)H * 64;
            kq0 = *(const float4*)(keys + h0);
            kq1 = *(const float4*)(keys + h1);
            vq0 = *(const float4*)(values + h0);
            vq1 = *(const float4*)(values + h1);
            mk0 = mrow[nn]; mk1 = mrow[nn + 1];
        }
        __syncthreads();
        const f16x8 afr = lds_load8(&VT[buf][wave * 16 + l15][quad * 8]);
        #pragma unroll
        for (int dt = 0; dt < 4; ++dt) {
            const f16x8 bfr = lds_load8(&KT[buf][dt * 16 + l15][quad * 8]);
            acc[dt] = __builtin_amdgcn_mfma_f32_16x16x32_f16(afr, bfr, acc[dt], 0, 0, 0);
        }
    }

    // KV output: D row = m = 16*wave + 4*quad + reg, col = d = 16*dt + l15
    float* kvb = kv + (size_t)bh * 4096;
    #pragma unroll
    for (int dt = 0; dt < 4; ++dt) {
        #pragma unroll
        for (int reg = 0; reg < 4; ++reg) {
            const int m = wave * 16 + quad * 4 + reg;
            atomicAdd(kvb + m * 64 + dt * 16 + l15, acc[dt][reg]);
        }
    }
    // Ksum: reduce over p within wave, then across waves via LDS
    #pragma unroll
    for (int dd = 0; dd < 4; ++dd) {
        float v = ksacc[dd];
        v += __shfl_xor(v, 16);
        v += __shfl_xor(v, 32);
        if (lane < 16) Ksw[wave][lane * 4 + dd] = v;
    }
    __syncthreads();
    if (t < 64) {
        atomicAdd(ksum + bh * 64 + t, Ksw[0][t] + Ksw[1][t] + Ksw[2][t] + Ksw[3][t]);
    }
}

// ---------------------------------------------------------------------------
// Pass 2 (MFMA, LDS-free): out[n][m] = (fQ[n]·KV[m]) / (fQ[n]·Ksum + eps)
// A-frag (fQ) and B-frag (KV) layouts are both memory-contiguous (8 consecutive
// d per lane), so everything loads straight from global; featmap in-register.
// grid (BH, 32), block 256; each wave owns 64 rows = 4 MFMA row-tiles.
// ---------------------------------------------------------------------------
__global__ __launch_bounds__(256, 4) void out_pass(
    const float* __restrict__ queries,
    const float* __restrict__ kv,
    const float* __restrict__ ksum,
    float* __restrict__ out)
{
    const int bh = blockIdx.x, b = bh >> 3, h = bh & 7;
    const int t = threadIdx.x;
    const int wave = t >> 6, lane = t & 63;
    const int quad = lane >> 4, l15 = lane & 15;
    const int n0 = blockIdx.y * 256 + wave * 64;

    // B-frags: bfr[mt][ks] = KV[m=mt*16+l15][d = ks*32+quad*8 .. +8)
    const float* kvb = kv + (size_t)bh * 4096;
    f16x8 bfr[4][2];
    #pragma unroll
    for (int mt = 0; mt < 4; ++mt) {
        #pragma unroll
        for (int ks = 0; ks < 2; ++ks) {
            const float* p = kvb + (mt * 16 + l15) * 64 + ks * 32 + quad * 8;
            const float4 x0 = *(const float4*)p;
            const float4 x1 = *(const float4*)(p + 4);
            bfr[mt][ks] = pack8(x0, x1);
        }
    }
    // z-tile: Ksum in column 0 only
    f16x8 bz[2];
    #pragma unroll
    for (int ks = 0; ks < 2; ++ks) {
        const float* zp = ksum + bh * 64 + ks * 32 + quad * 8;
        const float4 z0 = *(const float4*)zp;
        const float4 z1 = *(const float4*)(zp + 4);
        const f16x8 zf = pack8(z0, z1);
        #pragma unroll
        for (int j = 0; j < 8; ++j)
            bz[ks][j] = (l15 == 0) ? zf[j] : (f16)0.f;
    }

    // Q tiles: row = n0 + nt*16 + l15; 2-deep prefetch
    const size_t rs = (size_t)H * 64;   // 512 floats between n-rows
    const float* q0p = queries + ((size_t)((b * N + n0) + 0) * H + h) * 64;

    float4 qa, qb, qc, qd;
    {
        const float* qp = q0p + (size_t)l15 * rs + quad * 8;
        qa = *(const float4*)qp;       qb = *(const float4*)(qp + 4);
        qc = *(const float4*)(qp + 32); qd = *(const float4*)(qp + 36);
    }

    #pragma unroll
    for (int nt = 0; nt < 4; ++nt) {
        // featmap + cvt current tile
        float4 fa, fb, fc, fd;
        fa.x = featmap(qa.x); fa.y = featmap(qa.y); fa.z = featmap(qa.z); fa.w = featmap(qa.w);
        fb.x = featmap(qb.x); fb.y = featmap(qb.y); fb.z = featmap(qb.z); fb.w = featmap(qb.w);
        fc.x = featmap(qc.x); fc.y = featmap(qc.y); fc.z = featmap(qc.z); fc.w = featmap(qc.w);
        fd.x = featmap(qd.x); fd.y = featmap(qd.y); fd.z = featmap(qd.z); fd.w = featmap(qd.w);
        const f16x8 afr0 = pack8(fa, fb);
        const f16x8 afr1 = pack8(fc, fd);

        // prefetch next tile
        if (nt < 3) {
            const float* qp = q0p + (size_t)((nt + 1) * 16 + l15) * rs + quad * 8;
            qa = *(const float4*)qp;       qb = *(const float4*)(qp + 4);
            qc = *(const float4*)(qp + 32); qd = *(const float4*)(qp + 36);
        }

        f32x4 acc[4];
        #pragma unroll
        for (int i = 0; i < 4; ++i) acc[i] = (f32x4){0.f, 0.f, 0.f, 0.f};
        f32x4 az = (f32x4){0.f, 0.f, 0.f, 0.f};

        #pragma unroll
        for (int mt = 0; mt < 4; ++mt)
            acc[mt] = __builtin_amdgcn_mfma_f32_16x16x32_f16(afr0, bfr[mt][0], acc[mt], 0, 0, 0);
        az = __builtin_amdgcn_mfma_f32_16x16x32_f16(afr0, bz[0], az, 0, 0, 0);
        #pragma unroll
        for (int mt = 0; mt < 4; ++mt)
            acc[mt] = __builtin_amdgcn_mfma_f32_16x16x32_f16(afr1, bfr[mt][1], acc[mt], 0, 0, 0);
        az = __builtin_amdgcn_mfma_f32_16x16x32_f16(afr1, bz[1], az, 0, 0, 0);

        // epilogue: denominator is col 0 (l15==0) of az; C/D row = quad*4+reg
        #pragma unroll
        for (int reg = 0; reg < 4; ++reg) {
            const float den = __shfl(az[reg], lane & 48);
            const float zin = 1.0f / (den + EPSF);
            const int nn = n0 + nt * 16 + quad * 4 + reg;
            float* op = out + ((size_t)((b * N + nn) * H + h)) * 64 + l15;
            #pragma unroll
            for (int mt = 0; mt < 4; ++mt)
                op[mt * 16] = acc[mt][reg] * zin;
        }
    }
}

extern "C" void kernel_launch(void* const* d_in, const int* in_sizes, int n_in,
                              void* d_out, int out_size, void* d_ws, size_t ws_size,
                              hipStream_t stream)
{
    const float* q    = (const float*)d_in[0];
    const float* k    = (const float*)d_in[1];
    const float* v    = (const float*)d_in[2];
    const float* mask = (const float*)d_in[3];
    float* out = (float*)d_out;

    float* kv = (float*)d_ws;                  // [BH][64][64]
    float* ks = kv + (size_t)BH * 64 * 64;     // [BH][64]

    hipMemsetAsync(d_ws, 0, (size_t)(BH * 64 * 64 + BH * 64) * sizeof(float), stream);
    kv_pass<<<dim3(BH, N / ROWS1), 256, 0, stream>>>(k, v, mask, kv, ks);
    out_pass<<<dim3(BH, 32), 256, 0, stream>>>(q, kv, ks, out);
}